// Round 2
// baseline (4504.161 us; speedup 1.0000x reference)
//
#include <hip/hip_runtime.h>
#include <hip/hip_bf16.h>
#include <math.h>

// Problem dims (fixed by reference)
#define B 32
#define S 256
#define H 768
#define KG 200
#define FF 3072
#define LH 128
#define D 968        // H + KG
#define NT 11
#define G4 512       // 4*LH
#define START_TAG 9
#define END_TAG 10

// ---------------------------------------------------------------------------
// Kernel 1: kg projection + LayerNorm + tanh + attention score (per token)
// 8 tokens per block to amortize kg_W1 traffic.
#define TPB 8
__global__ __launch_bounds__(256) void kg_score_kernel(
    const float* __restrict__ in,      // (B,S,D)
    const float* __restrict__ W1,      // (H,KG)
    const float* __restrict__ b1,      // (H)
    const float* __restrict__ ln_g,    // (H)
    const float* __restrict__ ln_b,    // (H)
    const float* __restrict__ W2,      // (1,H)
    const float* __restrict__ b2,      // (1)
    float* __restrict__ scores)        // (B*S)
{
    __shared__ float kg_s[TPB][KG];
    __shared__ float red[256];
    __shared__ float red2[256];
    int tid = threadIdx.x;
    int tok0 = blockIdx.x * TPB;

    for (int i = tid; i < TPB * KG; i += 256) {
        int tk = i / KG, k = i % KG;
        kg_s[tk][k] = in[(size_t)(tok0 + tk) * D + H + k];
    }
    __syncthreads();

    float acc[3][TPB];
    for (int ii = 0; ii < 3; ++ii) {
        int i = ii * 256 + tid;          // 0..767
        float a[TPB];
        float bv = b1[i];
#pragma unroll
        for (int tk = 0; tk < TPB; ++tk) a[tk] = bv;
        for (int k = 0; k < KG; ++k) {
            float w = W1[(size_t)i * KG + k];
#pragma unroll
            for (int tk = 0; tk < TPB; ++tk) a[tk] += kg_s[tk][k] * w;
        }
#pragma unroll
        for (int tk = 0; tk < TPB; ++tk) acc[ii][tk] = a[tk];
    }
    float g3[3], bb3[3], w2[3];
    for (int ii = 0; ii < 3; ++ii) {
        int i = ii * 256 + tid;
        g3[ii] = ln_g[i]; bb3[ii] = ln_b[i]; w2[ii] = W2[i];
    }

    for (int tk = 0; tk < TPB; ++tk) {
        float s1 = acc[0][tk] + acc[1][tk] + acc[2][tk];
        float s2 = acc[0][tk]*acc[0][tk] + acc[1][tk]*acc[1][tk] + acc[2][tk]*acc[2][tk];
        red[tid] = s1; red2[tid] = s2;
        __syncthreads();
        for (int st = 128; st > 0; st >>= 1) {
            if (tid < st) { red[tid] += red[tid + st]; red2[tid] += red2[tid + st]; }
            __syncthreads();
        }
        float mu  = red[0] * (1.f / H);
        float var = red2[0] * (1.f / H) - mu * mu;
        float rstd = rsqrtf(var + 1e-5f);
        __syncthreads();
        float sc = 0.f;
#pragma unroll
        for (int ii = 0; ii < 3; ++ii)
            sc += tanhf((acc[ii][tk] - mu) * rstd * g3[ii] + bb3[ii]) * w2[ii];
        red[tid] = sc;
        __syncthreads();
        for (int st = 128; st > 0; st >>= 1) {
            if (tid < st) red[tid] += red[tid + st];
            __syncthreads();
        }
        if (tid == 0) scores[tok0 + tk] = red[0] + b2[0];
        __syncthreads();
    }
}

// ---------------------------------------------------------------------------
// Kernel 2: softmax over sequence dim per batch (S == 256 == blockDim)
__global__ __launch_bounds__(256) void softmax_kernel(
    const float* __restrict__ scores, float* __restrict__ attw)
{
    int b = blockIdx.x, tid = threadIdx.x;
    __shared__ float red[256];
    float v = scores[b * S + tid];
    red[tid] = v; __syncthreads();
    for (int st = 128; st > 0; st >>= 1) {
        if (tid < st) red[tid] = fmaxf(red[tid], red[tid + st]);
        __syncthreads();
    }
    float m = red[0]; __syncthreads();
    float e = expf(v - m);
    red[tid] = e; __syncthreads();
    for (int st = 128; st > 0; st >>= 1) {
        if (tid < st) red[tid] += red[tid + st];
        __syncthreads();
    }
    attw[b * S + tid] = e / red[0];
}

// ---------------------------------------------------------------------------
// Kernel 3: assemble combined = [bert, kg*(1+attw)]
__global__ __launch_bounds__(256) void combine_kernel(
    const float* __restrict__ in, const float* __restrict__ attw,
    float* __restrict__ outc)
{
    size_t idx = (size_t)blockIdx.x * 256 + threadIdx.x;
    const size_t total = (size_t)B * S * D;
    if (idx >= total) return;
    int d = (int)(idx % D);
    size_t tok = idx / D;
    float v = in[idx];
    if (d >= H) v *= (1.f + attw[tok]);
    outc[idx] = v;
}

// ---------------------------------------------------------------------------
// Generic tiled fp32 GEMM: C(M,N) = act(A(M,K) @ W(N,K)^T + bias) [+ res]
// act: 0 = none, 1 = relu.
#define BM 64
#define BN 64
#define BKK 16
__global__ __launch_bounds__(256) void gemm_kernel(
    const float* __restrict__ A, const float* __restrict__ W,
    const float* __restrict__ bias, const float* __restrict__ res,
    float* __restrict__ C, int M, int N, int K, int act)
{
    __shared__ float As[BKK][BM + 1];
    __shared__ float Ws[BKK][BN + 1];
    int bm = blockIdx.y * BM, bn = blockIdx.x * BN;
    int tid = threadIdx.x;
    int tm = (tid / 16) * 4;
    int tn = (tid % 16) * 4;
    float acc[4][4] = {};

    for (int k0 = 0; k0 < K; k0 += BKK) {
        for (int i = tid; i < BM * BKK; i += 256) {
            int m = i / BKK, k = i % BKK;
            float v = 0.f;
            if (k0 + k < K) v = A[(size_t)(bm + m) * K + k0 + k];
            As[k][m] = v;
        }
        for (int i = tid; i < BN * BKK; i += 256) {
            int n = i / BKK, k = i % BKK;
            float v = 0.f;
            if (bn + n < N && k0 + k < K) v = W[(size_t)(bn + n) * K + k0 + k];
            Ws[k][n] = v;
        }
        __syncthreads();
#pragma unroll
        for (int k = 0; k < BKK; ++k) {
            float a[4], w[4];
#pragma unroll
            for (int i = 0; i < 4; ++i) a[i] = As[k][tm + i];
#pragma unroll
            for (int j = 0; j < 4; ++j) w[j] = Ws[k][tn + j];
#pragma unroll
            for (int i = 0; i < 4; ++i)
#pragma unroll
                for (int j = 0; j < 4; ++j) acc[i][j] += a[i] * w[j];
        }
        __syncthreads();
    }
#pragma unroll
    for (int i = 0; i < 4; ++i) {
        int m = bm + tm + i;
        if (m >= M) continue;
#pragma unroll
        for (int j = 0; j < 4; ++j) {
            int n = bn + tn + j;
            if (n >= N) continue;
            float v = acc[i][j] + bias[n];
            if (act == 1) v = fmaxf(v, 0.f);
            if (res) v += res[(size_t)m * N + n];
            C[(size_t)m * N + n] = v;
        }
    }
}

// ---------------------------------------------------------------------------
// LSTM recurrence: one block per (sample, direction). 512 threads = 1 gate
// element each; Whh row cached in registers; h broadcast via LDS.
__global__ __launch_bounds__(512) void lstm_kernel(
    const float* __restrict__ pre_f, const float* __restrict__ pre_b,
    const float* __restrict__ whh_f, const float* __restrict__ whh_b,
    float* __restrict__ out)   // (B,S,2*LH)
{
    int b = blockIdx.x & 31;
    int dir = blockIdx.x >> 5;
    const float* pre = dir ? pre_b : pre_f;
    const float* whh = dir ? whh_b : whh_f;
    int g = threadIdx.x;

    float wh[LH];
#pragma unroll
    for (int k = 0; k < LH; k += 4) {
        float4 v = *(const float4*)(whh + (size_t)g * LH + k);
        wh[k] = v.x; wh[k+1] = v.y; wh[k+2] = v.z; wh[k+3] = v.w;
    }

    __shared__ __align__(16) float h_s[LH];
    __shared__ float g_s[G4];
    if (g < LH) h_s[g] = 0.f;
    float c = 0.f;
    __syncthreads();

    for (int step = 0; step < S; ++step) {
        int t = dir ? (S - 1 - step) : step;
        float acc = pre[(size_t)(b * S + t) * G4 + g];
#pragma unroll
        for (int k = 0; k < LH; k += 4) {
            float4 hv = *(const float4*)(h_s + k);
            acc += wh[k] * hv.x + wh[k+1] * hv.y + wh[k+2] * hv.z + wh[k+3] * hv.w;
        }
        g_s[g] = acc;
        __syncthreads();
        if (g < LH) {
            float ig = 1.f / (1.f + expf(-g_s[g]));
            float fg = 1.f / (1.f + expf(-g_s[LH + g]));
            float gg = tanhf(g_s[2 * LH + g]);
            float og = 1.f / (1.f + expf(-g_s[3 * LH + g]));
            c = fg * c + ig * gg;
            float h = og * tanhf(c);
            h_s[g] = h;
            out[(size_t)(b * S + t) * (2 * LH) + dir * LH + g] = h;
        }
        __syncthreads();
    }
}

// ---------------------------------------------------------------------------
// CRF NLL per sample: one 64-thread block per sample.
__global__ __launch_bounds__(64) void crf_kernel(
    const float* __restrict__ em,      // (B,S,NT)
    const int* __restrict__ labels,    // (B,S)
    const int* __restrict__ mask,      // (B,S)
    const float* __restrict__ trans,   // (NT,NT)
    float* __restrict__ nll)           // (B)
{
    int b = blockIdx.x, tid = threadIdx.x;
    __shared__ float tr[NT * NT];
    __shared__ float alpha[NT];
    __shared__ float red[64];
    __shared__ float gold_s;

    // BUGFIX (round 1): NT*NT = 121 > 64 threads; previous single-shot load
    // left tr[64..120] as uninitialized LDS garbage -> logZ inflated by
    // ~256 * (garbage) -> absmax 1712. Strided loop covers all 121.
    for (int i = tid; i < NT * NT; i += 64) tr[i] = trans[i];
    __syncthreads();

    float emit = 0.f, pair = 0.f, lenf = 0.f;
    for (int s = tid; s < S; s += 64) {
        int lab = labels[b * S + s];
        float mf = (float)mask[b * S + s];
        emit += em[(size_t)(b * S + s) * NT + lab] * mf;
        lenf += mf;
        if (s >= 1) {
            int lp = labels[b * S + s - 1];
            pair += tr[lp * NT + lab] * mf;
        }
    }
    red[tid] = emit; __syncthreads();
    for (int st = 32; st > 0; st >>= 1) { if (tid < st) red[tid] += red[tid + st]; __syncthreads(); }
    float emit_tot = red[0]; __syncthreads();
    red[tid] = pair; __syncthreads();
    for (int st = 32; st > 0; st >>= 1) { if (tid < st) red[tid] += red[tid + st]; __syncthreads(); }
    float pair_tot = red[0]; __syncthreads();
    red[tid] = lenf; __syncthreads();
    for (int st = 32; st > 0; st >>= 1) { if (tid < st) red[tid] += red[tid + st]; __syncthreads(); }
    float len_tot = red[0]; __syncthreads();

    if (tid == 0) {
        int len_i = (int)(len_tot + 0.5f);
        int last = labels[b * S + len_i - 1];
        gold_s = tr[START_TAG * NT + labels[b * S]] + emit_tot + pair_tot
               + tr[last * NT + END_TAG];
    }
    if (tid < NT) alpha[tid] = tr[START_TAG * NT + tid] + em[(size_t)(b * S) * NT + tid];
    __syncthreads();

    for (int t = 1; t < S; ++t) {
        float newv = 0.f;
        if (tid < NT) {
            float vals[NT];
            float m = -1e30f;
#pragma unroll
            for (int i2 = 0; i2 < NT; ++i2) {
                float v = alpha[i2] + tr[i2 * NT + tid];
                vals[i2] = v;
                m = fmaxf(m, v);
            }
            float ssum = 0.f;
#pragma unroll
            for (int i2 = 0; i2 < NT; ++i2) ssum += expf(vals[i2] - m);
            newv = m + logf(ssum) + em[(size_t)(b * S + t) * NT + tid];
            if (!(mask[b * S + t] > 0)) newv = alpha[tid];
        }
        __syncthreads();
        if (tid < NT) alpha[tid] = newv;
        __syncthreads();
    }

    if (tid < NT) red[tid] = alpha[tid] + tr[tid * NT + END_TAG];
    __syncthreads();
    if (tid == 0) {
        float m = -1e30f;
        for (int j = 0; j < NT; ++j) m = fmaxf(m, red[j]);
        float ssum = 0.f;
        for (int j = 0; j < NT; ++j) ssum += expf(red[j] - m);
        float logZ = m + logf(ssum);
        nll[b] = logZ - gold_s;
    }
}

__global__ void mean_kernel(const float* __restrict__ nll, float* __restrict__ out)
{
    if (threadIdx.x == 0) {
        float s = 0.f;
        for (int i = 0; i < B; ++i) s += nll[i];
        out[0] = s / (float)B;
    }
}

// ---------------------------------------------------------------------------
extern "C" void kernel_launch(void* const* d_in, const int* in_sizes, int n_in,
                              void* d_out, int out_size, void* d_ws, size_t ws_size,
                              hipStream_t stream)
{
    const float* in_emb = (const float*)d_in[0];
    const int*   mask   = (const int*)d_in[1];
    const int*   labels = (const int*)d_in[2];
    const float* kg_W1  = (const float*)d_in[3];
    const float* kg_b1  = (const float*)d_in[4];
    const float* ln_g   = (const float*)d_in[5];
    const float* ln_b   = (const float*)d_in[6];
    const float* kg_W2  = (const float*)d_in[7];
    const float* kg_b2  = (const float*)d_in[8];
    const float* ff_W1  = (const float*)d_in[9];
    const float* ff_b1  = (const float*)d_in[10];
    const float* ff_W2  = (const float*)d_in[11];
    const float* ff_b2  = (const float*)d_in[12];
    const float* Wih0f  = (const float*)d_in[13];
    const float* Whh0f  = (const float*)d_in[14];
    const float* b0f    = (const float*)d_in[15];
    const float* Wih0b  = (const float*)d_in[16];
    const float* Whh0b  = (const float*)d_in[17];
    const float* b0b    = (const float*)d_in[18];
    const float* Wih1f  = (const float*)d_in[19];
    const float* Whh1f  = (const float*)d_in[20];
    const float* b1f    = (const float*)d_in[21];
    const float* Wih1b  = (const float*)d_in[22];
    const float* Whh1b  = (const float*)d_in[23];
    const float* b1b    = (const float*)d_in[24];
    const float* cls_W  = (const float*)d_in[25];
    const float* cls_b  = (const float*)d_in[26];
    const float* trans  = (const float*)d_in[27];

    float* ws = (float*)d_ws;
    // Workspace layout (floats). "big" region first holds ff1, then is reused
    // for LSTM intermediates (they fit: 20.97M < 25.17M floats).
    size_t off = 0;
    float* combined = ws + off; off += (size_t)B * S * D;          // 7,929,856
    float* big      = ws + off; off += (size_t)B * S * FF;         // 25,165,824
    float* ff1   = big;
    float* pre0f = big;
    float* pre0b = big + 4194304;
    float* x1    = big + 8388608;
    float* pre1f = big + 10485760;
    float* pre1b = big + 14680064;
    float* x2    = big + 18874368;
    float* scores = ws + off; off += (size_t)B * S;
    float* attw   = ws + off; off += (size_t)B * S;
    float* emis   = ws + off; off += (size_t)B * S * NT;
    float* nll    = ws + off; off += B;
    (void)ws_size; (void)in_sizes; (void)n_in; (void)out_size;

    // 1. kg projection + LN + tanh + attention scores
    kg_score_kernel<<<(B * S) / TPB, 256, 0, stream>>>(
        in_emb, kg_W1, kg_b1, ln_g, ln_b, kg_W2, kg_b2, scores);
    // 2. softmax over sequence
    softmax_kernel<<<B, 256, 0, stream>>>(scores, attw);
    // 3. combined assembly
    {
        size_t total = (size_t)B * S * D;
        combine_kernel<<<(int)((total + 255) / 256), 256, 0, stream>>>(in_emb, attw, combined);
    }
    // 4. FF layer: ff1 = relu(combined @ W1^T + b1)
    gemm_kernel<<<dim3(FF / BN, (B * S) / BM), 256, 0, stream>>>(
        combined, ff_W1, ff_b1, nullptr, ff1, B * S, FF, D, 1);
    // 5. x = ff1 @ W2^T + b2 + combined   (in place over combined)
    gemm_kernel<<<dim3((D + BN - 1) / BN, (B * S) / BM), 256, 0, stream>>>(
        ff1, ff_W2, ff_b2, combined, combined, B * S, D, FF, 0);
    // 6-7. LSTM layer 0 input projections
    gemm_kernel<<<dim3(G4 / BN, (B * S) / BM), 256, 0, stream>>>(
        combined, Wih0f, b0f, nullptr, pre0f, B * S, G4, D, 0);
    gemm_kernel<<<dim3(G4 / BN, (B * S) / BM), 256, 0, stream>>>(
        combined, Wih0b, b0b, nullptr, pre0b, B * S, G4, D, 0);
    // 8. LSTM layer 0 recurrence (both directions)
    lstm_kernel<<<2 * B, G4, 0, stream>>>(pre0f, pre0b, Whh0f, Whh0b, x1);
    // 9-10. LSTM layer 1 input projections
    gemm_kernel<<<dim3(G4 / BN, (B * S) / BM), 256, 0, stream>>>(
        x1, Wih1f, b1f, nullptr, pre1f, B * S, G4, 2 * LH, 0);
    gemm_kernel<<<dim3(G4 / BN, (B * S) / BM), 256, 0, stream>>>(
        x1, Wih1b, b1b, nullptr, pre1b, B * S, G4, 2 * LH, 0);
    // 11. LSTM layer 1 recurrence
    lstm_kernel<<<2 * B, G4, 0, stream>>>(pre1f, pre1b, Whh1f, Whh1b, x2);
    // 12. emissions
    gemm_kernel<<<dim3(1, (B * S) / BM), 256, 0, stream>>>(
        x2, cls_W, cls_b, nullptr, emis, B * S, NT, 2 * LH, 0);
    // 13. CRF per-sample NLL
    crf_kernel<<<B, 64, 0, stream>>>(emis, labels, mask, trans, nll);
    // 14. mean
    mean_kernel<<<1, 64, 0, stream>>>(nll, (float*)d_out);
}

// Round 3
// 1726.477 us; speedup vs baseline: 2.6089x; 2.6089x over previous
//
#include <hip/hip_runtime.h>
#include <hip/hip_bf16.h>
#include <math.h>

// Problem dims (fixed by reference)
#define B 32
#define S 256
#define H 768
#define KG 200
#define FF 3072
#define LH 128
#define D 968        // H + KG
#define DP 1024      // D padded to multiple of 32 (and N-pad for FF2 out)
#define NT 11
#define G4 512       // 4*LH
#define START_TAG 9
#define END_TAG 10
#define M_TOK 8192   // B*S

typedef __attribute__((ext_vector_type(8))) short short8;
typedef __attribute__((ext_vector_type(4))) float f32x4;

// ---------------------------------------------------------------------------
// async global->LDS, 16B per lane. LDS dest must be wave-uniform base;
// HW scatters lane i to base + i*16.
__device__ __forceinline__ void gl_lds16(const void* gptr, void* lptr) {
    __builtin_amdgcn_global_load_lds(
        (const __attribute__((address_space(1))) void*)gptr,
        (__attribute__((address_space(3))) void*)lptr,
        16, 0, 0);
}

// ---------------------------------------------------------------------------
// Kernel 1: kg projection + LayerNorm + tanh + attention score (per token)
#define TPB 8
__global__ __launch_bounds__(256) void kg_score_kernel(
    const float* __restrict__ in,      // (B,S,D)
    const float* __restrict__ W1,      // (H,KG)
    const float* __restrict__ b1,
    const float* __restrict__ ln_g,
    const float* __restrict__ ln_b,
    const float* __restrict__ W2,      // (1,H)
    const float* __restrict__ b2,
    float* __restrict__ scores)        // (B*S)
{
    __shared__ float kg_s[TPB][KG];
    __shared__ float red[256];
    __shared__ float red2[256];
    int tid = threadIdx.x;
    int tok0 = blockIdx.x * TPB;

    for (int i = tid; i < TPB * KG; i += 256) {
        int tk = i / KG, k = i % KG;
        kg_s[tk][k] = in[(size_t)(tok0 + tk) * D + H + k];
    }
    __syncthreads();

    float acc[3][TPB];
    for (int ii = 0; ii < 3; ++ii) {
        int i = ii * 256 + tid;          // 0..767
        float a[TPB];
        float bv = b1[i];
#pragma unroll
        for (int tk = 0; tk < TPB; ++tk) a[tk] = bv;
        for (int k = 0; k < KG; ++k) {
            float w = W1[(size_t)i * KG + k];
#pragma unroll
            for (int tk = 0; tk < TPB; ++tk) a[tk] += kg_s[tk][k] * w;
        }
#pragma unroll
        for (int tk = 0; tk < TPB; ++tk) acc[ii][tk] = a[tk];
    }
    float g3[3], bb3[3], w2[3];
    for (int ii = 0; ii < 3; ++ii) {
        int i = ii * 256 + tid;
        g3[ii] = ln_g[i]; bb3[ii] = ln_b[i]; w2[ii] = W2[i];
    }

    for (int tk = 0; tk < TPB; ++tk) {
        float s1 = acc[0][tk] + acc[1][tk] + acc[2][tk];
        float s2 = acc[0][tk]*acc[0][tk] + acc[1][tk]*acc[1][tk] + acc[2][tk]*acc[2][tk];
        red[tid] = s1; red2[tid] = s2;
        __syncthreads();
        for (int st = 128; st > 0; st >>= 1) {
            if (tid < st) { red[tid] += red[tid + st]; red2[tid] += red2[tid + st]; }
            __syncthreads();
        }
        float mu  = red[0] * (1.f / H);
        float var = red2[0] * (1.f / H) - mu * mu;
        float rstd = rsqrtf(var + 1e-5f);
        __syncthreads();
        float sc = 0.f;
#pragma unroll
        for (int ii = 0; ii < 3; ++ii)
            sc += tanhf((acc[ii][tk] - mu) * rstd * g3[ii] + bb3[ii]) * w2[ii];
        red[tid] = sc;
        __syncthreads();
        for (int st = 128; st > 0; st >>= 1) {
            if (tid < st) red[tid] += red[tid + st];
            __syncthreads();
        }
        if (tid == 0) scores[tok0 + tk] = red[0] + b2[0];
        __syncthreads();
    }
}

// ---------------------------------------------------------------------------
// Kernel 2: softmax over sequence dim per batch
__global__ __launch_bounds__(256) void softmax_kernel(
    const float* __restrict__ scores, float* __restrict__ attw)
{
    int b = blockIdx.x, tid = threadIdx.x;
    __shared__ float red[256];
    float v = scores[b * S + tid];
    red[tid] = v; __syncthreads();
    for (int st = 128; st > 0; st >>= 1) {
        if (tid < st) red[tid] = fmaxf(red[tid], red[tid + st]);
        __syncthreads();
    }
    float m = red[0]; __syncthreads();
    float e = expf(v - m);
    red[tid] = e; __syncthreads();
    for (int st = 128; st > 0; st >>= 1) {
        if (tid < st) red[tid] += red[tid + st];
        __syncthreads();
    }
    attw[b * S + tid] = e / red[0];
}

// ---------------------------------------------------------------------------
// Kernel 3: combined = [bert, kg*(1+attw)]; writes fp32 compact (stride D)
// AND bf16 K-padded (stride DP, pad cols zero) for the MFMA GEMM.
__global__ __launch_bounds__(256) void combine2_kernel(
    const float* __restrict__ in, const float* __restrict__ attw,
    float* __restrict__ comb32, __hip_bfloat16* __restrict__ Ab)
{
    size_t idx = (size_t)blockIdx.x * 256 + threadIdx.x;   // over M_TOK*DP
    if (idx >= (size_t)M_TOK * DP) return;
    int d = (int)(idx & (DP - 1));
    size_t tok = idx >> 10;
    if (d < D) {
        float v = in[tok * D + d];
        if (d >= H) v *= (1.f + attw[tok]);
        comb32[tok * D + d] = v;
        Ab[idx] = __float2bfloat16(v);
    } else {
        Ab[idx] = __float2bfloat16(0.f);
    }
}

// ---------------------------------------------------------------------------
// Weight cast: src (N,K) fp32 -> dst (Np,Kp) bf16, zero pad.
__global__ __launch_bounds__(256) void castpad2d_kernel(
    const float* __restrict__ src, __hip_bfloat16* __restrict__ dst,
    int N, int K, int Np, int Kp)
{
    size_t idx = (size_t)blockIdx.x * 256 + threadIdx.x;
    if (idx >= (size_t)Np * Kp) return;
    int n = (int)(idx / Kp), k = (int)(idx % Kp);
    float v = (n < N && k < K) ? src[(size_t)n * K + k] : 0.f;
    dst[idx] = __float2bfloat16(v);
}

__global__ __launch_bounds__(256) void cast1d_kernel(
    const float* __restrict__ src, __hip_bfloat16* __restrict__ dst, int n)
{
    int idx = blockIdx.x * 256 + threadIdx.x;
    if (idx < n) dst[idx] = __float2bfloat16(src[idx]);
}

// ---------------------------------------------------------------------------
// bf16 MFMA GEMM (m97 structure): C(M,Np) = act(A(M,Kp) @ W(Np,Kp)^T + bias)
//   [+ res fp32 (M,res_ld)], cols >= N_real forced to 0.
// 128x128 tile, BK=32, 256 threads = 4 waves, each wave 64x64 via 4x4
// mfma_f32_16x16x32_bf16. Staging via global_load_lds width=16.
// flags: bit0 = relu, bit1 = bf16 output (else fp32).
__global__ __launch_bounds__(256) void mfma_gemm(
    const __hip_bfloat16* __restrict__ A,
    const __hip_bfloat16* __restrict__ Wb,
    const float* __restrict__ bias,
    const float* __restrict__ res, int res_ld,
    void* __restrict__ Cout,
    int Np, int Kp, int N_real, int flags)
{
    __shared__ short As[128 * 32];
    __shared__ short Bs[128 * 32];
    const int tid  = threadIdx.x;
    const int wave = tid >> 6;
    const int lane = tid & 63;
    const int bm = blockIdx.y * 128, bn = blockIdx.x * 128;
    // staging: chunk c covers tile rows c*16..c*16+15; lane -> (row, col8)
    const int sr = lane >> 2;           // 0..15
    const int sc = (lane & 3) * 8;      // 0,8,16,24
    // fragment indexing
    const int fr = lane & 15;
    const int fq = lane >> 4;           // quad
    const int wm = (wave >> 1) * 64, wn = (wave & 1) * 64;

    f32x4 acc[4][4];
#pragma unroll
    for (int i = 0; i < 4; ++i)
#pragma unroll
        for (int j = 0; j < 4; ++j) acc[i][j] = (f32x4){0.f, 0.f, 0.f, 0.f};

    const __hip_bfloat16* ga0 = A  + (size_t)(bm + wave * 32      + sr) * Kp + sc;
    const __hip_bfloat16* ga1 = A  + (size_t)(bm + wave * 32 + 16 + sr) * Kp + sc;
    const __hip_bfloat16* gb0 = Wb + (size_t)(bn + wave * 32      + sr) * Kp + sc;
    const __hip_bfloat16* gb1 = Wb + (size_t)(bn + wave * 32 + 16 + sr) * Kp + sc;
    short* lA0 = &As[(wave * 2 + 0) * 512];
    short* lA1 = &As[(wave * 2 + 1) * 512];
    short* lB0 = &Bs[(wave * 2 + 0) * 512];
    short* lB1 = &Bs[(wave * 2 + 1) * 512];

    for (int k0 = 0; k0 < Kp; k0 += 32) {
        gl_lds16(ga0 + k0, lA0);
        gl_lds16(ga1 + k0, lA1);
        gl_lds16(gb0 + k0, lB0);
        gl_lds16(gb1 + k0, lB1);
        __syncthreads();   // compiler drains vmcnt(0) before s_barrier

        short8 af[4], bfr[4];
#pragma unroll
        for (int mi = 0; mi < 4; ++mi)
            af[mi] = *(const short8*)&As[(wm + mi * 16 + fr) * 32 + fq * 8];
#pragma unroll
        for (int ni = 0; ni < 4; ++ni)
            bfr[ni] = *(const short8*)&Bs[(wn + ni * 16 + fr) * 32 + fq * 8];
#pragma unroll
        for (int mi = 0; mi < 4; ++mi)
#pragma unroll
            for (int ni = 0; ni < 4; ++ni)
                acc[mi][ni] = __builtin_amdgcn_mfma_f32_16x16x32_bf16(
                    af[mi], bfr[ni], acc[mi][ni], 0, 0, 0);
        __syncthreads();
    }

    const bool relu = flags & 1;
    const bool obf  = flags & 2;
#pragma unroll
    for (int mi = 0; mi < 4; ++mi) {
#pragma unroll
        for (int ni = 0; ni < 4; ++ni) {
#pragma unroll
            for (int r = 0; r < 4; ++r) {
                int m = bm + wm + mi * 16 + fq * 4 + r;
                int n = bn + wn + ni * 16 + fr;
                float v = acc[mi][ni][r];
                if (n < N_real) {
                    v += bias[n];
                    if (relu) v = fmaxf(v, 0.f);
                    if (res) v += res[(size_t)m * res_ld + n];
                } else {
                    v = 0.f;
                }
                if (obf)
                    ((__hip_bfloat16*)Cout)[(size_t)m * Np + n] = __float2bfloat16(v);
                else
                    ((float*)Cout)[(size_t)m * Np + n] = v;
            }
        }
    }
}

// ---------------------------------------------------------------------------
// small fp32 GEMM kept for emissions only (N=11, K=256)
#define BM 64
#define BN 64
#define BKK 16
__global__ __launch_bounds__(256) void gemm_kernel(
    const float* __restrict__ A, const float* __restrict__ W,
    const float* __restrict__ bias, const float* __restrict__ res,
    float* __restrict__ C, int M, int N, int K, int act)
{
    __shared__ float As[BKK][BM + 1];
    __shared__ float Ws[BKK][BN + 1];
    int bm = blockIdx.y * BM, bn = blockIdx.x * BN;
    int tid = threadIdx.x;
    int tm = (tid / 16) * 4;
    int tn = (tid % 16) * 4;
    float acc[4][4] = {};

    for (int k0 = 0; k0 < K; k0 += BKK) {
        for (int i = tid; i < BM * BKK; i += 256) {
            int m = i / BKK, k = i % BKK;
            float v = 0.f;
            if (k0 + k < K) v = A[(size_t)(bm + m) * K + k0 + k];
            As[k][m] = v;
        }
        for (int i = tid; i < BN * BKK; i += 256) {
            int n = i / BKK, k = i % BKK;
            float v = 0.f;
            if (bn + n < N && k0 + k < K) v = W[(size_t)(bn + n) * K + k0 + k];
            Ws[k][n] = v;
        }
        __syncthreads();
#pragma unroll
        for (int k = 0; k < BKK; ++k) {
            float a[4], w[4];
#pragma unroll
            for (int i = 0; i < 4; ++i) a[i] = As[k][tm + i];
#pragma unroll
            for (int j = 0; j < 4; ++j) w[j] = Ws[k][tn + j];
#pragma unroll
            for (int i = 0; i < 4; ++i)
#pragma unroll
                for (int j = 0; j < 4; ++j) acc[i][j] += a[i] * w[j];
        }
        __syncthreads();
    }
#pragma unroll
    for (int i = 0; i < 4; ++i) {
        int m = bm + tm + i;
        if (m >= M) continue;
#pragma unroll
        for (int j = 0; j < 4; ++j) {
            int n = bn + tn + j;
            if (n >= N) continue;
            float v = acc[i][j] + bias[n];
            if (act == 1) v = fmaxf(v, 0.f);
            if (res) v += res[(size_t)m * N + n];
            C[(size_t)m * N + n] = v;
        }
    }
}

// ---------------------------------------------------------------------------
// LSTM recurrence: one block per (sample, direction).
__global__ __launch_bounds__(512) void lstm_kernel(
    const float* __restrict__ pre_f, const float* __restrict__ pre_b,
    const float* __restrict__ whh_f, const float* __restrict__ whh_b,
    float* __restrict__ out)   // (B,S,2*LH)
{
    int b = blockIdx.x & 31;
    int dir = blockIdx.x >> 5;
    const float* pre = dir ? pre_b : pre_f;
    const float* whh = dir ? whh_b : whh_f;
    int g = threadIdx.x;

    float wh[LH];
#pragma unroll
    for (int k = 0; k < LH; k += 4) {
        float4 v = *(const float4*)(whh + (size_t)g * LH + k);
        wh[k] = v.x; wh[k+1] = v.y; wh[k+2] = v.z; wh[k+3] = v.w;
    }

    __shared__ __align__(16) float h_s[LH];
    __shared__ float g_s[G4];
    if (g < LH) h_s[g] = 0.f;
    float c = 0.f;
    __syncthreads();

    for (int step = 0; step < S; ++step) {
        int t = dir ? (S - 1 - step) : step;
        float acc = pre[(size_t)(b * S + t) * G4 + g];
#pragma unroll
        for (int k = 0; k < LH; k += 4) {
            float4 hv = *(const float4*)(h_s + k);
            acc += wh[k] * hv.x + wh[k+1] * hv.y + wh[k+2] * hv.z + wh[k+3] * hv.w;
        }
        g_s[g] = acc;
        __syncthreads();
        if (g < LH) {
            float ig = 1.f / (1.f + expf(-g_s[g]));
            float fg = 1.f / (1.f + expf(-g_s[LH + g]));
            float gg = tanhf(g_s[2 * LH + g]);
            float og = 1.f / (1.f + expf(-g_s[3 * LH + g]));
            c = fg * c + ig * gg;
            float h = og * tanhf(c);
            h_s[g] = h;
            out[(size_t)(b * S + t) * (2 * LH) + dir * LH + g] = h;
        }
        __syncthreads();
    }
}

// ---------------------------------------------------------------------------
// CRF NLL per sample
__global__ __launch_bounds__(64) void crf_kernel(
    const float* __restrict__ em, const int* __restrict__ labels,
    const int* __restrict__ mask, const float* __restrict__ trans,
    float* __restrict__ nll)
{
    int b = blockIdx.x, tid = threadIdx.x;
    __shared__ float tr[NT * NT];
    __shared__ float alpha[NT];
    __shared__ float red[64];
    __shared__ float gold_s;

    for (int i = tid; i < NT * NT; i += 64) tr[i] = trans[i];
    __syncthreads();

    float emit = 0.f, pair = 0.f, lenf = 0.f;
    for (int s = tid; s < S; s += 64) {
        int lab = labels[b * S + s];
        float mf = (float)mask[b * S + s];
        emit += em[(size_t)(b * S + s) * NT + lab] * mf;
        lenf += mf;
        if (s >= 1) {
            int lp = labels[b * S + s - 1];
            pair += tr[lp * NT + lab] * mf;
        }
    }
    red[tid] = emit; __syncthreads();
    for (int st = 32; st > 0; st >>= 1) { if (tid < st) red[tid] += red[tid + st]; __syncthreads(); }
    float emit_tot = red[0]; __syncthreads();
    red[tid] = pair; __syncthreads();
    for (int st = 32; st > 0; st >>= 1) { if (tid < st) red[tid] += red[tid + st]; __syncthreads(); }
    float pair_tot = red[0]; __syncthreads();
    red[tid] = lenf; __syncthreads();
    for (int st = 32; st > 0; st >>= 1) { if (tid < st) red[tid] += red[tid + st]; __syncthreads(); }
    float len_tot = red[0]; __syncthreads();

    if (tid == 0) {
        int len_i = (int)(len_tot + 0.5f);
        int last = labels[b * S + len_i - 1];
        gold_s = tr[START_TAG * NT + labels[b * S]] + emit_tot + pair_tot
               + tr[last * NT + END_TAG];
    }
    if (tid < NT) alpha[tid] = tr[START_TAG * NT + tid] + em[(size_t)(b * S) * NT + tid];
    __syncthreads();

    for (int t = 1; t < S; ++t) {
        float newv = 0.f;
        if (tid < NT) {
            float vals[NT];
            float m = -1e30f;
#pragma unroll
            for (int i2 = 0; i2 < NT; ++i2) {
                float v = alpha[i2] + tr[i2 * NT + tid];
                vals[i2] = v;
                m = fmaxf(m, v);
            }
            float ssum = 0.f;
#pragma unroll
            for (int i2 = 0; i2 < NT; ++i2) ssum += expf(vals[i2] - m);
            newv = m + logf(ssum) + em[(size_t)(b * S + t) * NT + tid];
            if (!(mask[b * S + t] > 0)) newv = alpha[tid];
        }
        __syncthreads();
        if (tid < NT) alpha[tid] = newv;
        __syncthreads();
    }

    if (tid < NT) red[tid] = alpha[tid] + tr[tid * NT + END_TAG];
    __syncthreads();
    if (tid == 0) {
        float m = -1e30f;
        for (int j = 0; j < NT; ++j) m = fmaxf(m, red[j]);
        float ssum = 0.f;
        for (int j = 0; j < NT; ++j) ssum += expf(red[j] - m);
        float logZ = m + logf(ssum);
        nll[b] = logZ - gold_s;
    }
}

__global__ void mean_kernel(const float* __restrict__ nll, float* __restrict__ out)
{
    if (threadIdx.x == 0) {
        float s = 0.f;
        for (int i = 0; i < B; ++i) s += nll[i];
        out[0] = s / (float)B;
    }
}

// ---------------------------------------------------------------------------
extern "C" void kernel_launch(void* const* d_in, const int* in_sizes, int n_in,
                              void* d_out, int out_size, void* d_ws, size_t ws_size,
                              hipStream_t stream)
{
    const float* in_emb = (const float*)d_in[0];
    const int*   mask   = (const int*)d_in[1];
    const int*   labels = (const int*)d_in[2];
    const float* kg_W1  = (const float*)d_in[3];
    const float* kg_b1  = (const float*)d_in[4];
    const float* ln_g   = (const float*)d_in[5];
    const float* ln_b   = (const float*)d_in[6];
    const float* kg_W2  = (const float*)d_in[7];
    const float* kg_b2  = (const float*)d_in[8];
    const float* ff_W1  = (const float*)d_in[9];
    const float* ff_b1  = (const float*)d_in[10];
    const float* ff_W2  = (const float*)d_in[11];
    const float* ff_b2  = (const float*)d_in[12];
    const float* Wih0f  = (const float*)d_in[13];
    const float* Whh0f  = (const float*)d_in[14];
    const float* b0f    = (const float*)d_in[15];
    const float* Wih0b  = (const float*)d_in[16];
    const float* Whh0b  = (const float*)d_in[17];
    const float* b0b    = (const float*)d_in[18];
    const float* Wih1f  = (const float*)d_in[19];
    const float* Whh1f  = (const float*)d_in[20];
    const float* b1f    = (const float*)d_in[21];
    const float* Wih1b  = (const float*)d_in[22];
    const float* Whh1b  = (const float*)d_in[23];
    const float* b1b    = (const float*)d_in[24];
    const float* cls_W  = (const float*)d_in[25];
    const float* cls_b  = (const float*)d_in[26];
    const float* trans  = (const float*)d_in[27];
    (void)ws_size; (void)in_sizes; (void)n_in; (void)out_size;

    // ---- workspace arena (byte offsets; total ~131.2 MB, proven available) --
    char* wsb = (char*)d_ws;
    size_t o = 0;
    float*          comb32 = (float*)(wsb + o);            o += (size_t)M_TOK * D  * 4;  // 31,719,424
    __hip_bfloat16* Ab     = (__hip_bfloat16*)(wsb + o);   size_t ab_off = o; o += (size_t)M_TOK * DP * 2;  // 16,777,216
    char*           big    = wsb + o;                      o += (size_t)M_TOK * FF * 2;  // 50,331,648
    __hip_bfloat16* xb     = (__hip_bfloat16*)(wsb + o);   o += (size_t)M_TOK * DP * 2;  // 16,777,216
    __hip_bfloat16* Wbff1  = (__hip_bfloat16*)(wsb + o);   o += (size_t)FF * DP * 2;     // 6,291,456
    __hip_bfloat16* Wbff2  = (__hip_bfloat16*)(wsb + o);   o += (size_t)DP * FF * 2;     // 6,291,456
    __hip_bfloat16* Wb0f   = (__hip_bfloat16*)(wsb + o);   o += (size_t)G4 * DP * 2;     // 1,048,576
    __hip_bfloat16* Wb0b   = (__hip_bfloat16*)(wsb + o);   o += (size_t)G4 * DP * 2;
    __hip_bfloat16* Wb1f   = (__hip_bfloat16*)(wsb + o);   o += (size_t)G4 * 256 * 2;    // 262,144
    __hip_bfloat16* Wb1b   = (__hip_bfloat16*)(wsb + o);   o += (size_t)G4 * 256 * 2;
    float*          scores = (float*)(wsb + o);            o += (size_t)M_TOK * 4;
    float*          attw   = (float*)(wsb + o);            o += (size_t)M_TOK * 4;
    float*          emis   = (float*)(wsb + o);            o += (size_t)M_TOK * NT * 4;
    float*          nll    = (float*)(wsb + o);            o += B * 4;
    // big region reuse timeline:
    __hip_bfloat16* ff1b  = (__hip_bfloat16*)big;                      // FF1 out (dead after FF2)
    float*          pre0f = (float*)(big + 0);                         // after FF2
    float*          pre0b = (float*)(big + 16777216);
    float*          x1    = (float*)(big + 33554432);                  // LSTM0 out fp32
    __hip_bfloat16* x1b   = (__hip_bfloat16*)(big + 41943040);         // bf16 cast of x1
    float*          pre1f = (float*)(big + 0);                         // after LSTM0
    float*          pre1b = (float*)(big + 16777216);
    float*          x2    = (float*)(wsb + ab_off);                    // reuse Ab (dead after FF1)

    // ---- weight casts (independent; padded K, zero fill) ----
    castpad2d_kernel<<<(FF * DP + 255) / 256, 256, 0, stream>>>(ff_W1, Wbff1, FF, D,  FF, DP);
    castpad2d_kernel<<<(DP * FF + 255) / 256, 256, 0, stream>>>(ff_W2, Wbff2, D,  FF, DP, FF);
    castpad2d_kernel<<<(G4 * DP + 255) / 256, 256, 0, stream>>>(Wih0f, Wb0f, G4, D, G4, DP);
    castpad2d_kernel<<<(G4 * DP + 255) / 256, 256, 0, stream>>>(Wih0b, Wb0b, G4, D, G4, DP);
    castpad2d_kernel<<<(G4 * 256 + 255) / 256, 256, 0, stream>>>(Wih1f, Wb1f, G4, 256, G4, 256);
    castpad2d_kernel<<<(G4 * 256 + 255) / 256, 256, 0, stream>>>(Wih1b, Wb1b, G4, 256, G4, 256);

    // ---- attention front-end ----
    kg_score_kernel<<<M_TOK / TPB, 256, 0, stream>>>(
        in_emb, kg_W1, kg_b1, ln_g, ln_b, kg_W2, kg_b2, scores);
    softmax_kernel<<<B, 256, 0, stream>>>(scores, attw);
    combine2_kernel<<<(M_TOK * DP + 255) / 256, 256, 0, stream>>>(in_emb, attw, comb32, Ab);

    // ---- FF block (bf16 MFMA) ----
    // ff1b = relu(Ab @ Wff1^T + b1), bf16 out
    mfma_gemm<<<dim3(FF / 128, M_TOK / 128), 256, 0, stream>>>(
        Ab, Wbff1, ff_b1, nullptr, 0, ff1b, FF, DP, FF, 1 | 2);
    // xb = ff1b @ Wff2^T + b2 + comb32 (fp32 residual), bf16 out, N padded 968->1024
    mfma_gemm<<<dim3(DP / 128, M_TOK / 128), 256, 0, stream>>>(
        ff1b, Wbff2, ff_b2, comb32, D, xb, DP, FF, D, 2);

    // ---- LSTM layer 0 ----
    mfma_gemm<<<dim3(G4 / 128, M_TOK / 128), 256, 0, stream>>>(
        xb, Wb0f, b0f, nullptr, 0, pre0f, G4, DP, G4, 0);
    mfma_gemm<<<dim3(G4 / 128, M_TOK / 128), 256, 0, stream>>>(
        xb, Wb0b, b0b, nullptr, 0, pre0b, G4, DP, G4, 0);
    lstm_kernel<<<2 * B, G4, 0, stream>>>(pre0f, pre0b, Whh0f, Whh0b, x1);
    cast1d_kernel<<<(M_TOK * 256 + 255) / 256, 256, 0, stream>>>(x1, x1b, M_TOK * 256);

    // ---- LSTM layer 1 ----
    mfma_gemm<<<dim3(G4 / 128, M_TOK / 128), 256, 0, stream>>>(
        x1b, Wb1f, b1f, nullptr, 0, pre1f, G4, 256, G4, 0);
    mfma_gemm<<<dim3(G4 / 128, M_TOK / 128), 256, 0, stream>>>(
        x1b, Wb1b, b1b, nullptr, 0, pre1b, G4, 256, G4, 0);
    lstm_kernel<<<2 * B, G4, 0, stream>>>(pre1f, pre1b, Whh1f, Whh1b, x2);

    // ---- emissions (tiny, fp32) + CRF + mean ----
    gemm_kernel<<<dim3(1, M_TOK / BM), 256, 0, stream>>>(
        x2, cls_W, cls_b, nullptr, emis, M_TOK, NT, 2 * LH, 0);
    crf_kernel<<<B, 64, 0, stream>>>(emis, labels, mask, trans, nll);
    mean_kernel<<<1, 64, 0, stream>>>(nll, (float*)d_out);
}